// Round 9
// baseline (179.293 us; speedup 1.0000x reference)
//
#include <hip/hip_runtime.h>
#include <hip/hip_bf16.h>

typedef unsigned short u16;
typedef __attribute__((ext_vector_type(8))) short bf16x8;
typedef __attribute__((ext_vector_type(4))) float f32x4;

#define B_ 16
#define CIN 256
#define COUT 256
#define NPIX 4096
#define E_ 8
#define HP 66            // halo-padded width/height
#define PPIX (HP*HP)     // 4356 padded pixels per sample
#define KTOT 2304        // 9 * 256
#define NKT 36           // K-tiles of 64

__device__ __forceinline__ u16 f2bf(float f){
    union { float f; unsigned int u; } v; v.f = f;
    return (u16)((v.u + 0x7FFFu + ((v.u >> 16) & 1u)) >> 16);
}

__device__ __forceinline__ void gload(const u16* g, u16* l){
    __builtin_amdgcn_global_load_lds(
        (const __attribute__((address_space(1))) unsigned int*)g,
        (__attribute__((address_space(3))) unsigned int*)l, 16, 0, 0);
}

// -------- 1) transpose+convert x -> xt2, fused pool + fused border-zero --------
__global__ void k_xt(const float* __restrict__ x, u16* __restrict__ xt2,
                     float* __restrict__ pooled){
    __shared__ float tile[64][65];
    int bid = blockIdx.x;
    int t = threadIdx.x;

    // fused halo-border zeroing (blocks 0..519 cover 16 samples x 260 border px)
    if (bid < 520){
        int gid = bid*256 + t;
        int u4 = gid & 31;
        int pl = gid >> 5;
        if (pl < B_*260){
            int bb = pl / 260;
            int pi = pl - bb*260;
            int yy, xx;
            if (pi < 66)      { yy = 0;  xx = pi; }
            else if (pi < 132){ yy = 65; xx = pi - 66; }
            else { int q = pi - 132; yy = 1 + (q >> 1); xx = (q & 1) ? 65 : 0; }
            uint4 z = {0u,0u,0u,0u};
            *(uint4*)(xt2 + ((size_t)bb*PPIX + yy*HP + xx)*CIN + u4*8) = z;
        }
    }

    int b = bid >> 8, ct = (bid >> 6) & 3, pt = bid & 63;
    int c0 = ct*64, p0 = pt*64;
    #pragma unroll
    for (int iter = 0; iter < 4; ++iter){
        int idx = t*4 + iter*1024;
        int r = idx >> 6, c4 = idx & 63;
        float4 v = *(const float4*)(x + ((size_t)(b*CIN + c0 + r))*NPIX + p0 + c4);
        tile[r][c4+0] = v.x; tile[r][c4+1] = v.y; tile[r][c4+2] = v.z; tile[r][c4+3] = v.w;
        float rs = v.x + v.y + v.z + v.w;
        #pragma unroll
        for (int off = 1; off < 16; off <<= 1) rs += __shfl_xor(rs, off, 64);
        if ((t & 15) == 0) atomicAdd(&pooled[b*CIN + c0 + r], rs);
    }
    __syncthreads();
    #pragma unroll
    for (int iter = 0; iter < 4; ++iter){
        int idx = t*4 + iter*1024;
        int pr = idx >> 6, cc = idx & 63;
        ushort4 u;
        u.x = f2bf(tile[cc+0][pr]);
        u.y = f2bf(tile[cc+1][pr]);
        u.z = f2bf(tile[cc+2][pr]);
        u.w = f2bf(tile[cc+3][pr]);
        int p = p0 + pr;
        int yy = p >> 6, xx = p & 63;
        *(ushort4*)(xt2 + ((size_t)b*PPIX + (yy+1)*HP + (xx+1))*CIN + c0 + cc) = u;
    }
}

// -------- 2) aggregated weights + fused routing + aggregated bias --------
__global__ void k_aggw(const float* __restrict__ weight, const float* __restrict__ pooled,
                       const float* __restrict__ rw, const float* __restrict__ rb,
                       const float* __restrict__ bias,
                       u16* __restrict__ aggw, float* __restrict__ aggb)
{
    __shared__ float wls[E_][2304];
    __shared__ float r_s[B_*E_];
    int o = blockIdx.x, t = threadIdx.x;

    if (t < B_*E_){
        int b = t >> 3, e = t & 7;
        const float4* pp = (const float4*)(pooled + b*CIN);
        const float4* wp = (const float4*)(rw + e*CIN);
        float s = 0.f;
        #pragma unroll
        for (int i = 0; i < 64; ++i){
            float4 a = pp[i], c = wp[i];
            s += a.x*c.x + a.y*c.y + a.z*c.z + a.w*c.w;
        }
        s = s * (1.0f/(float)NPIX) + rb[e];
        r_s[t] = 1.0f/(1.0f + __expf(-s));
    }
    #pragma unroll
    for (int e = 0; e < E_; ++e){
        const float4* src = (const float4*)(weight + ((size_t)(e*COUT + o))*2304);
        float4* dst = (float4*)wls[e];
        #pragma unroll
        for (int i = 0; i < 3; ++i){
            int idx = t + i*256;
            if (idx < 576) dst[idx] = src[idx];
        }
    }
    __syncthreads();

    if (t < B_){
        float s = 0.f;
        #pragma unroll
        for (int e = 0; e < E_; ++e) s += r_s[t*E_+e]*bias[e*COUT+o];
        aggb[t*COUT + o] = s;
    }

    float w[E_][9];
    #pragma unroll
    for (int e = 0; e < E_; ++e)
        #pragma unroll
        for (int tp = 0; tp < 9; ++tp) w[e][tp] = wls[e][t*9 + tp];
    for (int b = 0; b < B_; ++b){
        float acc[9];
        #pragma unroll
        for (int tp = 0; tp < 9; ++tp) acc[tp] = 0.f;
        #pragma unroll
        for (int e = 0; e < E_; ++e){
            float r = r_s[b*E_+e];
            #pragma unroll
            for (int tp = 0; tp < 9; ++tp) acc[tp] += r*w[e][tp];
        }
        #pragma unroll
        for (int tp = 0; tp < 9; ++tp)
            aggw[(((size_t)(b*COUT + o))*9 + tp)*CIN + t] = f2bf(acc[tp]);
    }
}

// -------- 3) 256x256 tile, BK=64: A-only LDS (3-buf), B global->reg, 1 barrier/tile --------
__global__ __launch_bounds__(512, 1) void k_conv(
    const u16* __restrict__ aggw, const u16* __restrict__ xt2,
    const float* __restrict__ aggb, float* __restrict__ out)
{
    __shared__ __align__(16) u16 lds[49152];   // 3 x (256x64 bf16 A panel = 32KB)

    int orig = blockIdx.x;
    int bid = (orig & 7)*32 + (orig >> 3);     // bijective XCD swizzle (256 % 8 == 0)

    int b  = bid >> 4;
    int nt = bid & 15;
    int y0 = nt << 2;

    int t = threadIdx.x;
    int lane = t & 63;
    int w = t >> 6;
    int wm = (w >> 2) << 7;      // 0 / 128
    int wn = (w & 3) << 6;       // 0 / 64 / 128 / 192
    int l16 = lane & 15;
    int kh4 = lane >> 4;

    // A LDS read: slot(row,s) holds logical granule s^(row&7); want g=kh4 (+4 for khalf1)
    int ck0 = ((kh4     ^ (l16 & 7)) << 3);
    int ck1 = (((kh4+4) ^ (l16 & 7)) << 3);

    // A staging: wave w rows [w*32, w*32+32), instr i adds 8 rows; lane: row +(l>>3), slot l&7
    int arow = w*32 + (lane >> 3);
    int agl  = (((lane & 7) ^ (lane >> 3)) << 3);
    const u16* aS = aggw + (size_t)b*COUT*9*CIN + (size_t)arow*KTOT + agl;
    int aD = w*2048 + lane*8;    // u16 offset within one 16384-u16 buffer (linear dest)

    // B per-lane base: pixel row py fixed per wave, px = l16 (+16*nf uniform)
    int py = y0 + (wn >> 6);
    const u16* bBase = xt2 + ((size_t)b*PPIX + (size_t)py*HP + l16)*CIN + kh4*8;

    f32x4 acc[8][4];
    #pragma unroll
    for (int i = 0; i < 8; ++i)
        #pragma unroll
        for (int j = 0; j < 4; ++j){
            f32x4 z = {0.f,0.f,0.f,0.f};
            acc[i][j] = z;
        }

    auto stageA = [&](int kt, int bufn){
        int tap = kt >> 2, c0 = (kt & 3) << 6;
        const u16* s = aS + tap*CIN + c0;
        u16* d = lds + bufn*16384 + aD;
        #pragma unroll
        for (int i = 0; i < 4; ++i)
            gload(s + (size_t)i*8*KTOT, d + i*512);
    };
    auto loadB = [&](int kt, bf16x8 (&dst)[4][2]){
        int tap = kt >> 2, c0 = (kt & 3) << 6;
        int kh = tap/3, kw = tap - 3*kh;
        int off = (kh*HP + kw)*CIN + c0;
        #pragma unroll
        for (int nf = 0; nf < 4; ++nf){
            dst[nf][0] = *(const bf16x8*)(bBase + off + nf*(16*CIN));
            dst[nf][1] = *(const bf16x8*)(bBase + off + nf*(16*CIN) + 32);
        }
    };

    bf16x8 bva[4][2], bvb[4][2];

    stageA(0, 0);                // 4 gloads
    stageA(1, 1);                // 4 gloads
    loadB(0, bva);               // 8 reg loads -> 16 VMEM in flight

    auto body = [&](int kt, bf16x8 (&cur)[4][2], bf16x8 (&nxt)[4][2]){
        // retire Ast(kt) (and older); keep B(kt) + Ast(kt+1) = 12 in flight
        asm volatile("s_waitcnt vmcnt(12)" ::: "memory");
        __builtin_amdgcn_s_barrier();
        int n1 = kt+1 < NKT ? kt+1 : NKT-1;
        int n2 = kt+2 < NKT ? kt+2 : NKT-1;
        loadB(n1, nxt);                       // 8 loads, used next tile
        stageA(n2, (kt+2)%3);                 // 4 gloads, used in 2 tiles
        const u16* LA = lds + (kt%3)*16384;
        #pragma unroll
        for (int ch = 0; ch < 4; ++ch){
            bf16x8 af[2][2];
            #pragma unroll
            for (int m2 = 0; m2 < 2; ++m2){
                int ro = (wm + (ch*2+m2)*16 + l16)*64;
                af[m2][0] = *(const bf16x8*)(LA + ro + ck0);
                af[m2][1] = *(const bf16x8*)(LA + ro + ck1);
            }
            asm volatile("s_waitcnt lgkmcnt(0)" ::: "memory");
            __builtin_amdgcn_sched_barrier(0);     // rule #18
            __builtin_amdgcn_s_setprio(1);
            #pragma unroll
            for (int m2 = 0; m2 < 2; ++m2)
                #pragma unroll
                for (int nf = 0; nf < 4; ++nf){
                    acc[ch*2+m2][nf] = __builtin_amdgcn_mfma_f32_16x16x32_bf16(
                        af[m2][0], cur[nf][0], acc[ch*2+m2][nf], 0, 0, 0);
                    acc[ch*2+m2][nf] = __builtin_amdgcn_mfma_f32_16x16x32_bf16(
                        af[m2][1], cur[nf][1], acc[ch*2+m2][nf], 0, 0, 0);
                }
            __builtin_amdgcn_s_setprio(0);
        }
    };

    for (int kt = 0; kt < NKT; kt += 2){   // NKT even: static cur/nxt reg sets
        body(kt,   bva, bvb);
        body(kt+1, bvb, bva);
    }

    const float* ab = aggb + b*COUT;
    float* outp = out + ((size_t)b*COUT)*NPIX + nt*256;
    #pragma unroll
    for (int mf8 = 0; mf8 < 8; ++mf8){
        #pragma unroll
        for (int v = 0; v < 4; ++v){
            int r = wm + mf8*16 + kh4*4 + v;
            float bias_r = ab[r];
            float* orow = outp + (size_t)r*NPIX;
            #pragma unroll
            for (int nf = 0; nf < 4; ++nf)
                orow[wn + nf*16 + l16] = acc[mf8][nf][v] + bias_r;
        }
    }
}

extern "C" void kernel_launch(void* const* d_in, const int* in_sizes, int n_in,
                              void* d_out, int out_size, void* d_ws, size_t ws_size,
                              hipStream_t stream)
{
    const float* x      = (const float*)d_in[0];
    const float* weight = (const float*)d_in[1];
    const float* bias   = (const float*)d_in[2];
    const float* rw     = (const float*)d_in[3];
    const float* rb     = (const float*)d_in[4];
    float* out = (float*)d_out;

    char* ws = (char*)d_ws;
    u16*   aggw    = (u16*)(ws);                          // 18,874,368 B
    u16*   xt2     = (u16*)(ws + 18874368);               // 35,684,352 B (halo 66x66)
    float* pooled  = (float*)(ws + 54558720);             // 16 KB
    float* aggb    = (float*)(ws + 54558720 + 16384);     // 16 KB

    hipMemsetAsync(pooled, 0, B_*CIN*sizeof(float), stream);
    k_xt   <<<4096, 256, 0, stream>>>(x, xt2, pooled);
    k_aggw <<<COUT, 256, 0, stream>>>(weight, pooled, rw, rb, bias, aggw, aggb);
    k_conv <<<256,  512, 0, stream>>>(aggw, xt2, aggb, out);
}

// Round 10
// 158.215 us; speedup vs baseline: 1.1332x; 1.1332x over previous
//
#include <hip/hip_runtime.h>
#include <hip/hip_bf16.h>

typedef unsigned short u16;
typedef __attribute__((ext_vector_type(8))) short bf16x8;
typedef __attribute__((ext_vector_type(8))) short short8;
typedef __attribute__((ext_vector_type(4))) float f32x4;

#define B_ 16
#define CIN 256
#define COUT 256
#define NPIX 4096
#define E_ 8
#define HP 66            // halo-padded width/height
#define KTOT 2304        // 9 * 256
#define NKT 36           // K-tiles of 64
// xt4 layout: [b][y' 66][g 32][x' 66][8k] bf16; strides (u16): x'=8, g=528, y'=16896, b=1115136
#define XG 528
#define XY 16896
#define XB 1115136

__device__ __forceinline__ u16 f2bf(float f){
    union { float f; unsigned int u; } v; v.f = f;
    return (u16)((v.u + 0x7FFFu + ((v.u >> 16) & 1u)) >> 16);
}

__device__ __forceinline__ void gload(const u16* g, u16* l){
    __builtin_amdgcn_global_load_lds(
        (const __attribute__((address_space(1))) unsigned int*)g,
        (__attribute__((address_space(3))) unsigned int*)l, 16, 0, 0);
}

// -------- 1) transpose+convert x -> xt4[b][y'][g][x'][8], fused pool + border-zero --------
__global__ void k_xt(const float* __restrict__ x, u16* __restrict__ xt4,
                     float* __restrict__ pooled){
    __shared__ float tile[64][65];
    int bid = blockIdx.x;
    int t = threadIdx.x;

    // fused halo-border zeroing: 520 blocks x 256 threads = 133120 = 16 samples x 8320 chunks
    if (bid < 520){
        int gid = bid*256 + t;
        int bb = gid / 8320;
        int r  = gid - bb*8320;
        int yy, gg, xx;
        if (r < 4224){ yy = (r < 2112) ? 0 : 65; int rr = (r < 2112) ? r : r - 2112;
                       gg = rr / 66; xx = rr - gg*66; }
        else { int q = r - 4224; yy = 1 + (q >> 6); gg = (q >> 1) & 31; xx = (q & 1) * 65; }
        uint4 z = {0u,0u,0u,0u};
        *(uint4*)(xt4 + (size_t)bb*XB + (size_t)yy*XY + gg*XG + xx*8) = z;
    }

    int b = bid >> 8, ct = (bid >> 6) & 3, pt = bid & 63;   // pt = image row y
    int c0 = ct*64;
    #pragma unroll
    for (int iter = 0; iter < 4; ++iter){
        int idx = t*4 + iter*1024;
        int r = idx >> 6, c4 = idx & 63;
        float4 v = *(const float4*)(x + ((size_t)(b*CIN + c0 + r))*NPIX + pt*64 + c4);
        tile[r][c4+0] = v.x; tile[r][c4+1] = v.y; tile[r][c4+2] = v.z; tile[r][c4+3] = v.w;
        float rs = v.x + v.y + v.z + v.w;
        #pragma unroll
        for (int off = 1; off < 16; off <<= 1) rs += __shfl_xor(rs, off, 64);
        if ((t & 15) == 0) atomicAdd(&pooled[b*CIN + c0 + r], rs);
    }
    __syncthreads();
    // write: unit = (g_l 0..7, x 0..63); value[i] = channel c0+g_l*8+i at (row pt, col x)
    size_t obase = (size_t)b*XB + (size_t)(pt+1)*XY + (c0 >> 3)*XG + 8;  // +8: x'=x+1
    #pragma unroll
    for (int iter = 0; iter < 2; ++iter){
        int unit = t + iter*256;
        int g_l = unit >> 6, xx = unit & 63;
        short8 o;
        #pragma unroll
        for (int i = 0; i < 8; ++i) o[i] = (short)f2bf(tile[g_l*8 + i][xx]);
        *(short8*)(xt4 + obase + (size_t)g_l*XG + xx*8) = o;
    }
}

// -------- 2) aggregated weights + fused routing + aggregated bias --------
__global__ void k_aggw(const float* __restrict__ weight, const float* __restrict__ pooled,
                       const float* __restrict__ rw, const float* __restrict__ rb,
                       const float* __restrict__ bias,
                       u16* __restrict__ aggw, float* __restrict__ aggb)
{
    __shared__ float wls[E_][2304];
    __shared__ float r_s[B_*E_];
    int o = blockIdx.x, t = threadIdx.x;

    if (t < B_*E_){
        int b = t >> 3, e = t & 7;
        const float4* pp = (const float4*)(pooled + b*CIN);
        const float4* wp = (const float4*)(rw + e*CIN);
        float s = 0.f;
        #pragma unroll
        for (int i = 0; i < 64; ++i){
            float4 a = pp[i], c = wp[i];
            s += a.x*c.x + a.y*c.y + a.z*c.z + a.w*c.w;
        }
        s = s * (1.0f/(float)NPIX) + rb[e];
        r_s[t] = 1.0f/(1.0f + __expf(-s));
    }
    #pragma unroll
    for (int e = 0; e < E_; ++e){
        const float4* src = (const float4*)(weight + ((size_t)(e*COUT + o))*2304);
        float4* dst = (float4*)wls[e];
        #pragma unroll
        for (int i = 0; i < 3; ++i){
            int idx = t + i*256;
            if (idx < 576) dst[idx] = src[idx];
        }
    }
    __syncthreads();

    if (t < B_){
        float s = 0.f;
        #pragma unroll
        for (int e = 0; e < E_; ++e) s += r_s[t*E_+e]*bias[e*COUT+o];
        aggb[t*COUT + o] = s;
    }

    float w[E_][9];
    #pragma unroll
    for (int e = 0; e < E_; ++e)
        #pragma unroll
        for (int tp = 0; tp < 9; ++tp) w[e][tp] = wls[e][t*9 + tp];
    for (int b = 0; b < B_; ++b){
        float acc[9];
        #pragma unroll
        for (int tp = 0; tp < 9; ++tp) acc[tp] = 0.f;
        #pragma unroll
        for (int e = 0; e < E_; ++e){
            float r = r_s[b*E_+e];
            #pragma unroll
            for (int tp = 0; tp < 9; ++tp) acc[tp] += r*w[e][tp];
        }
        #pragma unroll
        for (int tp = 0; tp < 9; ++tp)
            aggw[(((size_t)(b*COUT + o))*9 + tp)*CIN + t] = f2bf(acc[tp]);
    }
}

// -------- 3) 256x256, BK=64: A in LDS (3-buf, swizzled), B coalesced global->reg --------
__global__ __launch_bounds__(512, 1) void k_conv(
    const u16* __restrict__ aggw, const u16* __restrict__ xt4,
    const float* __restrict__ aggb, float* __restrict__ out)
{
    __shared__ __align__(16) u16 lds[49152];   // 3 x (256x64 bf16 A panel = 32KB)

    int orig = blockIdx.x;
    int bid = (orig & 7)*32 + (orig >> 3);     // bijective XCD swizzle (256 % 8 == 0)

    int b  = bid >> 4;
    int nt = bid & 15;
    int y0 = nt << 2;

    int t = threadIdx.x;
    int lane = t & 63;
    int w = t >> 6;
    int wm = (w >> 2) << 7;      // 0 / 128
    int wn = (w & 3) << 6;       // 0 / 64 / 128 / 192
    int l16 = lane & 15;
    int kh4 = lane >> 4;

    // A LDS read swizzle (proven): slot(row,s) holds logical granule s^(row&7)
    int ck0 = ((kh4     ^ (l16 & 7)) << 3);
    int ck1 = (((kh4+4) ^ (l16 & 7)) << 3);

    // A staging (proven R9 pattern)
    int arow = w*32 + (lane >> 3);
    int agl  = (((lane & 7) ^ (lane >> 3)) << 3);
    const u16* aS = aggw + (size_t)b*COUT*9*CIN + (size_t)arow*KTOT + agl;
    int aD = w*2048 + lane*8;

    // B per-lane base in xt4: pixel row y_img = y0 + (wn>>6), col x = (wn&63)+nf*16+l16
    const u16* bB = xt4 + (size_t)b*XB + (size_t)(y0 + (wn >> 6))*XY
                        + kh4*XG + ((wn & 63) + l16)*8;

    f32x4 acc[8][4];
    #pragma unroll
    for (int i = 0; i < 8; ++i)
        #pragma unroll
        for (int j = 0; j < 4; ++j){
            f32x4 z = {0.f,0.f,0.f,0.f};
            acc[i][j] = z;
        }

    auto stageA = [&](int kt, int bufn){
        int tap = kt >> 2, c0 = (kt & 3) << 6;
        const u16* s = aS + tap*CIN + c0;
        u16* d = lds + bufn*16384 + aD;
        #pragma unroll
        for (int i = 0; i < 4; ++i)
            gload(s + (size_t)i*8*KTOT, d + i*512);
    };
    auto loadB = [&](int kt, bf16x8 (&dst)[4][2]){
        int tap = kt >> 2, c0g = (kt & 3) << 3;   // cin granule base (c0/8)
        int kh = tap/3, kw = tap - 3*kh;
        const u16* s = bB + (size_t)kh*XY + (size_t)c0g*XG + kw*8;
        #pragma unroll
        for (int nf = 0; nf < 4; ++nf){
            dst[nf][0] = *(const bf16x8*)(s + nf*128);
            dst[nf][1] = *(const bf16x8*)(s + nf*128 + 4*XG);
        }
    };

    bf16x8 bva[4][2], bvb[4][2];

    // prologue order matters for the vmcnt ledger: A(0)[4], B(0)[8], A(1)[4]
    stageA(0, 0);
    loadB(0, bva);
    stageA(1, 1);

    auto body = [&](int kt, bf16x8 (&cur)[4][2], bf16x8 (&nxt)[4][2]){
        // retire everything up to B(kt); keep A(kt+1)[4] in flight
        asm volatile("s_waitcnt vmcnt(4)" ::: "memory");
        __builtin_amdgcn_s_barrier();
        int n1 = kt+1 < NKT ? kt+1 : NKT-1;
        int n2 = kt+2 < NKT ? kt+2 : NKT-1;
        loadB(n1, nxt);                       // 8 loads, consumed next tile
        stageA(n2, (kt+2)%3);                 // 4 gloads, consumed in 2 tiles
        const u16* LA = lds + (kt%3)*16384;
        #pragma unroll
        for (int ch = 0; ch < 4; ++ch){
            bf16x8 af[2][2];
            #pragma unroll
            for (int m2 = 0; m2 < 2; ++m2){
                int ro = (wm + (ch*2+m2)*16 + l16)*64;
                af[m2][0] = *(const bf16x8*)(LA + ro + ck0);
                af[m2][1] = *(const bf16x8*)(LA + ro + ck1);
            }
            asm volatile("s_waitcnt lgkmcnt(0)" ::: "memory");
            __builtin_amdgcn_sched_barrier(0);     // rule #18
            __builtin_amdgcn_s_setprio(1);
            #pragma unroll
            for (int m2 = 0; m2 < 2; ++m2)
                #pragma unroll
                for (int nf = 0; nf < 4; ++nf){
                    acc[ch*2+m2][nf] = __builtin_amdgcn_mfma_f32_16x16x32_bf16(
                        af[m2][0], cur[nf][0], acc[ch*2+m2][nf], 0, 0, 0);
                    acc[ch*2+m2][nf] = __builtin_amdgcn_mfma_f32_16x16x32_bf16(
                        af[m2][1], cur[nf][1], acc[ch*2+m2][nf], 0, 0, 0);
                }
            __builtin_amdgcn_s_setprio(0);
        }
    };

    for (int kt = 0; kt < NKT; kt += 2){   // NKT even: static cur/nxt reg sets
        body(kt,   bva, bvb);
        body(kt+1, bvb, bva);
    }

    const float* ab = aggb + b*COUT;
    float* outp = out + ((size_t)b*COUT)*NPIX + nt*256;
    #pragma unroll
    for (int mf8 = 0; mf8 < 8; ++mf8){
        #pragma unroll
        for (int v = 0; v < 4; ++v){
            int r = wm + mf8*16 + kh4*4 + v;
            float bias_r = ab[r];
            float* orow = outp + (size_t)r*NPIX;
            #pragma unroll
            for (int nf = 0; nf < 4; ++nf)
                orow[wn + nf*16 + l16] = acc[mf8][nf][v] + bias_r;
        }
    }
}

extern "C" void kernel_launch(void* const* d_in, const int* in_sizes, int n_in,
                              void* d_out, int out_size, void* d_ws, size_t ws_size,
                              hipStream_t stream)
{
    const float* x      = (const float*)d_in[0];
    const float* weight = (const float*)d_in[1];
    const float* bias   = (const float*)d_in[2];
    const float* rw     = (const float*)d_in[3];
    const float* rb     = (const float*)d_in[4];
    float* out = (float*)d_out;

    char* ws = (char*)d_ws;
    u16*   aggw    = (u16*)(ws);                          // 18,874,368 B
    u16*   xt4     = (u16*)(ws + 18874368);               // 35,684,352 B
    float* pooled  = (float*)(ws + 54558720);             // 16 KB
    float* aggb    = (float*)(ws + 54558720 + 16384);     // 16 KB

    hipMemsetAsync(pooled, 0, B_*CIN*sizeof(float), stream);
    k_xt   <<<4096, 256, 0, stream>>>(x, xt4, pooled);
    k_aggw <<<COUT, 256, 0, stream>>>(weight, pooled, rw, rb, bias, aggw, aggb);
    k_conv <<<256,  512, 0, stream>>>(aggw, xt4, aggb, out);
}

// Round 11
// 156.259 us; speedup vs baseline: 1.1474x; 1.0125x over previous
//
#include <hip/hip_runtime.h>
#include <hip/hip_bf16.h>

typedef unsigned short u16;
typedef __attribute__((ext_vector_type(8))) short bf16x8;
typedef __attribute__((ext_vector_type(8))) short short8;
typedef __attribute__((ext_vector_type(4))) float f32x4;

#define B_ 16
#define CIN 256
#define COUT 256
#define NPIX 4096
#define E_ 8
#define HP 66            // halo-padded width/height
#define KTOT 2304        // 9 * 256
#define NKT 36           // K-tiles of 64
// xt4 layout: [b][y' 66][g 32][x' 66][8k] bf16; strides (u16): x'=8, g=528, y'=16896, b=1115136
#define XG 528
#define XY 16896
#define XB 1115136

__device__ __forceinline__ u16 f2bf(float f){
    union { float f; unsigned int u; } v; v.f = f;
    return (u16)((v.u + 0x7FFFu + ((v.u >> 16) & 1u)) >> 16);
}

__device__ __forceinline__ void gload(const u16* g, u16* l){
    __builtin_amdgcn_global_load_lds(
        (const __attribute__((address_space(1))) unsigned int*)g,
        (__attribute__((address_space(3))) unsigned int*)l, 16, 0, 0);
}

// -------- 1) transpose+convert x -> xt4[b][y'][g][x'][8], fused pool + border-zero --------
__global__ void k_xt(const float* __restrict__ x, u16* __restrict__ xt4,
                     float* __restrict__ pooled){
    __shared__ float tile[64][65];
    int bid = blockIdx.x;
    int t = threadIdx.x;

    // fused halo-border zeroing: 520 blocks x 256 threads = 16 samples x 8320 chunks
    if (bid < 520){
        int gid = bid*256 + t;
        int bb = gid / 8320;
        int r  = gid - bb*8320;
        int yy, gg, xx;
        if (r < 4224){ yy = (r < 2112) ? 0 : 65; int rr = (r < 2112) ? r : r - 2112;
                       gg = rr / 66; xx = rr - gg*66; }
        else { int q = r - 4224; yy = 1 + (q >> 6); gg = (q >> 1) & 31; xx = (q & 1) * 65; }
        uint4 z = {0u,0u,0u,0u};
        *(uint4*)(xt4 + (size_t)bb*XB + (size_t)yy*XY + gg*XG + xx*8) = z;
    }

    int b = bid >> 8, ct = (bid >> 6) & 3, pt = bid & 63;   // pt = image row y
    int c0 = ct*64;
    #pragma unroll
    for (int iter = 0; iter < 4; ++iter){
        int idx = t*4 + iter*1024;
        int r = idx >> 6, c4 = idx & 63;
        float4 v = *(const float4*)(x + ((size_t)(b*CIN + c0 + r))*NPIX + pt*64 + c4);
        tile[r][c4+0] = v.x; tile[r][c4+1] = v.y; tile[r][c4+2] = v.z; tile[r][c4+3] = v.w;
        float rs = v.x + v.y + v.z + v.w;
        #pragma unroll
        for (int off = 1; off < 16; off <<= 1) rs += __shfl_xor(rs, off, 64);
        if ((t & 15) == 0) atomicAdd(&pooled[b*CIN + c0 + r], rs);
    }
    __syncthreads();
    size_t obase = (size_t)b*XB + (size_t)(pt+1)*XY + (c0 >> 3)*XG + 8;  // +8: x'=x+1
    #pragma unroll
    for (int iter = 0; iter < 2; ++iter){
        int unit = t + iter*256;
        int g_l = unit >> 6, xx = unit & 63;
        short8 o;
        #pragma unroll
        for (int i = 0; i < 8; ++i) o[i] = (short)f2bf(tile[g_l*8 + i][xx]);
        *(short8*)(xt4 + obase + (size_t)g_l*XG + xx*8) = o;
    }
}

// -------- 2) aggregated weights + fused routing + aggregated bias --------
__global__ void k_aggw(const float* __restrict__ weight, const float* __restrict__ pooled,
                       const float* __restrict__ rw, const float* __restrict__ rb,
                       const float* __restrict__ bias,
                       u16* __restrict__ aggw, float* __restrict__ aggb)
{
    __shared__ float wls[E_][2304];
    __shared__ float r_s[B_*E_];
    int o = blockIdx.x, t = threadIdx.x;

    if (t < B_*E_){
        int b = t >> 3, e = t & 7;
        const float4* pp = (const float4*)(pooled + b*CIN);
        const float4* wp = (const float4*)(rw + e*CIN);
        float s = 0.f;
        #pragma unroll
        for (int i = 0; i < 64; ++i){
            float4 a = pp[i], c = wp[i];
            s += a.x*c.x + a.y*c.y + a.z*c.z + a.w*c.w;
        }
        s = s * (1.0f/(float)NPIX) + rb[e];
        r_s[t] = 1.0f/(1.0f + __expf(-s));
    }
    #pragma unroll
    for (int e = 0; e < E_; ++e){
        const float4* src = (const float4*)(weight + ((size_t)(e*COUT + o))*2304);
        float4* dst = (float4*)wls[e];
        #pragma unroll
        for (int i = 0; i < 3; ++i){
            int idx = t + i*256;
            if (idx < 576) dst[idx] = src[idx];
        }
    }
    __syncthreads();

    if (t < B_){
        float s = 0.f;
        #pragma unroll
        for (int e = 0; e < E_; ++e) s += r_s[t*E_+e]*bias[e*COUT+o];
        aggb[t*COUT + o] = s;
    }

    float w[E_][9];
    #pragma unroll
    for (int e = 0; e < E_; ++e)
        #pragma unroll
        for (int tp = 0; tp < 9; ++tp) w[e][tp] = wls[e][t*9 + tp];
    for (int b = 0; b < B_; ++b){
        float acc[9];
        #pragma unroll
        for (int tp = 0; tp < 9; ++tp) acc[tp] = 0.f;
        #pragma unroll
        for (int e = 0; e < E_; ++e){
            float r = r_s[b*E_+e];
            #pragma unroll
            for (int tp = 0; tp < 9; ++tp) acc[tp] += r*w[e][tp];
        }
        #pragma unroll
        for (int tp = 0; tp < 9; ++tp)
            aggw[(((size_t)(b*COUT + o))*9 + tp)*CIN + t] = f2bf(acc[tp]);
    }
}

// -------- 3) 256x256, BK=64: A in LDS (2-buf dbuf), B coalesced global->reg,
//            R4-style compiler-scheduled tile body, ONE __syncthreads per tile --------
__global__ __launch_bounds__(512, 1) void k_conv(
    const u16* __restrict__ aggw, const u16* __restrict__ xt4,
    const float* __restrict__ aggb, float* __restrict__ out)
{
    __shared__ __align__(16) u16 lds[32768];   // 2 x (256x64 bf16 A panel = 32KB)

    int orig = blockIdx.x;
    int bid = (orig & 7)*32 + (orig >> 3);     // bijective XCD swizzle (256 % 8 == 0)

    int b  = bid >> 4;
    int nt = bid & 15;
    int y0 = nt << 2;

    int t = threadIdx.x;
    int lane = t & 63;
    int w = t >> 6;
    int wm = (w >> 2) << 7;      // 0 / 128
    int wn = (w & 3) << 6;       // 0 / 64 / 128 / 192
    int l16 = lane & 15;
    int kh4 = lane >> 4;

    // A LDS read swizzle (proven): slot(row,s) holds logical granule s^(row&7)
    int ck0 = ((kh4     ^ (l16 & 7)) << 3);
    int ck1 = (((kh4+4) ^ (l16 & 7)) << 3);

    // A staging (proven): wave w rows [w*32, +32), 4 gloads each +8 rows
    int arow = w*32 + (lane >> 3);
    int agl  = (((lane & 7) ^ (lane >> 3)) << 3);
    const u16* aS = aggw + (size_t)b*COUT*9*CIN + (size_t)arow*KTOT + agl;
    int aD = w*2048 + lane*8;

    // B per-lane base in xt4 (proven coalesced): 4x256B segments per load
    const u16* bB = xt4 + (size_t)b*XB + (size_t)(y0 + (wn >> 6))*XY
                        + kh4*XG + ((wn & 63) + l16)*8;

    f32x4 acc[8][4];
    #pragma unroll
    for (int i = 0; i < 8; ++i)
        #pragma unroll
        for (int j = 0; j < 4; ++j){
            f32x4 z = {0.f,0.f,0.f,0.f};
            acc[i][j] = z;
        }

    auto stageA = [&](int kt, int bufn){
        int tap = kt >> 2, c0 = (kt & 3) << 6;
        const u16* s = aS + tap*CIN + c0;
        u16* d = lds + bufn*16384 + aD;
        #pragma unroll
        for (int i = 0; i < 4; ++i)
            gload(s + (size_t)i*8*KTOT, d + i*512);
    };
    auto loadB = [&](int kt, bf16x8 (&dst)[4][2]){
        int tap = kt >> 2, c0g = (kt & 3) << 3;
        int kh = tap/3, kw = tap - 3*kh;
        const u16* s = bB + (size_t)kh*XY + (size_t)c0g*XG + kw*8;
        #pragma unroll
        for (int nf = 0; nf < 4; ++nf){
            dst[nf][0] = *(const bf16x8*)(s + nf*128);
            dst[nf][1] = *(const bf16x8*)(s + nf*128 + 4*XG);
        }
    };

    bf16x8 bva[4][2], bvb[4][2];

    stageA(0, 0);
    loadB(0, bva);
    __syncthreads();             // tile 0 A staged; bva ready

    auto body = [&](int kt, bf16x8 (&cur)[4][2], bf16x8 (&nxt)[4][2]){
        // issue next tile's A-stage + B-loads first (covered by this tile's MFMAs)
        if (kt + 1 < NKT){
            stageA(kt + 1, (kt + 1) & 1);
            loadB(kt + 1, nxt);
        }
        const u16* LA = lds + (kt & 1)*16384;
        // per-chunk frag reads, NO manual lgkmcnt: compiler emits counted waits
        #pragma unroll
        for (int ch = 0; ch < 4; ++ch){
            bf16x8 af[2][2];
            #pragma unroll
            for (int m2 = 0; m2 < 2; ++m2){
                int ro = (wm + (ch*2+m2)*16 + l16)*64;
                af[m2][0] = *(const bf16x8*)(LA + ro + ck0);
                af[m2][1] = *(const bf16x8*)(LA + ro + ck1);
            }
            __builtin_amdgcn_s_setprio(1);
            #pragma unroll
            for (int m2 = 0; m2 < 2; ++m2)
                #pragma unroll
                for (int nf = 0; nf < 4; ++nf){
                    acc[ch*2+m2][nf] = __builtin_amdgcn_mfma_f32_16x16x32_bf16(
                        af[m2][0], cur[nf][0], acc[ch*2+m2][nf], 0, 0, 0);
                    acc[ch*2+m2][nf] = __builtin_amdgcn_mfma_f32_16x16x32_bf16(
                        af[m2][1], cur[nf][1], acc[ch*2+m2][nf], 0, 0, 0);
                }
            __builtin_amdgcn_s_setprio(0);
        }
        __syncthreads();         // drains stage(kt+1); next buffer ready
    };

    for (int kt = 0; kt < NKT; kt += 2){   // NKT even: static cur/nxt reg sets
        body(kt,   bva, bvb);
        body(kt+1, bvb, bva);
    }

    const float* ab = aggb + b*COUT;
    float* outp = out + ((size_t)b*COUT)*NPIX + nt*256;
    #pragma unroll
    for (int mf8 = 0; mf8 < 8; ++mf8){
        #pragma unroll
        for (int v = 0; v < 4; ++v){
            int r = wm + mf8*16 + kh4*4 + v;
            float bias_r = ab[r];
            float* orow = outp + (size_t)r*NPIX;
            #pragma unroll
            for (int nf = 0; nf < 4; ++nf)
                orow[wn + nf*16 + l16] = acc[mf8][nf][v] + bias_r;
        }
    }
}

extern "C" void kernel_launch(void* const* d_in, const int* in_sizes, int n_in,
                              void* d_out, int out_size, void* d_ws, size_t ws_size,
                              hipStream_t stream)
{
    const float* x      = (const float*)d_in[0];
    const float* weight = (const float*)d_in[1];
    const float* bias   = (const float*)d_in[2];
    const float* rw     = (const float*)d_in[3];
    const float* rb     = (const float*)d_in[4];
    float* out = (float*)d_out;

    char* ws = (char*)d_ws;
    u16*   aggw    = (u16*)(ws);                          // 18,874,368 B
    u16*   xt4     = (u16*)(ws + 18874368);               // 35,684,352 B
    float* pooled  = (float*)(ws + 54558720);             // 16 KB
    float* aggb    = (float*)(ws + 54558720 + 16384);     // 16 KB

    hipMemsetAsync(pooled, 0, B_*CIN*sizeof(float), stream);
    k_xt   <<<4096, 256, 0, stream>>>(x, xt4, pooled);
    k_aggw <<<COUT, 256, 0, stream>>>(weight, pooled, rw, rb, bias, aggw, aggb);
    k_conv <<<256,  512, 0, stream>>>(aggw, xt4, aggb, out);
}

// Round 12
// 120.023 us; speedup vs baseline: 1.4938x; 1.3019x over previous
//
#include <hip/hip_runtime.h>
#include <hip/hip_bf16.h>

typedef unsigned short u16;
typedef __attribute__((ext_vector_type(8))) short bf16x8;
typedef __attribute__((ext_vector_type(8))) short short8;
typedef __attribute__((ext_vector_type(4))) float f32x4;

#define B_ 16
#define CIN 256
#define COUT 256
#define NPIX 4096
#define E_ 8
#define HP 66            // halo-padded width/height
#define PPIX (HP*HP)     // 4356 padded pixels per sample
#define KTOT 2304        // 9 * 256
#define NKT 36           // K-tiles of 64

__device__ __forceinline__ u16 f2bf(float f){
    union { float f; unsigned int u; } v; v.f = f;
    return (u16)((v.u + 0x7FFFu + ((v.u >> 16) & 1u)) >> 16);
}

__device__ __forceinline__ void gload(const u16* g, u16* l){
    __builtin_amdgcn_global_load_lds(
        (const __attribute__((address_space(1))) unsigned int*)g,
        (__attribute__((address_space(3))) unsigned int*)l, 16, 0, 0);
}

// -------- 1) transpose+convert x -> xt2[b][(y+1)*66+(x+1)][cin] bf16,
//            fused avg-pool partial sums + fused halo-border zeroing --------
__global__ void k_xt(const float* __restrict__ x, u16* __restrict__ xt2,
                     float* __restrict__ pooled){
    __shared__ float tile[64][65];
    int bid = blockIdx.x;
    int t = threadIdx.x;

    // fused halo-border zeroing (blocks 0..519 cover 16 samples x 260 border px)
    if (bid < 520){
        int gid = bid*256 + t;
        int u4 = gid & 31;
        int pl = gid >> 5;
        if (pl < B_*260){
            int bb = pl / 260;
            int pi = pl - bb*260;
            int yy, xx;
            if (pi < 66)      { yy = 0;  xx = pi; }
            else if (pi < 132){ yy = 65; xx = pi - 66; }
            else { int q = pi - 132; yy = 1 + (q >> 1); xx = (q & 1) ? 65 : 0; }
            uint4 z = {0u,0u,0u,0u};
            *(uint4*)(xt2 + ((size_t)bb*PPIX + yy*HP + xx)*CIN + u4*8) = z;
        }
    }

    int b = bid >> 8, ct = (bid >> 6) & 3, pt = bid & 63;
    int c0 = ct*64, p0 = pt*64;
    #pragma unroll
    for (int iter = 0; iter < 4; ++iter){
        int idx = t*4 + iter*1024;
        int r = idx >> 6, c4 = idx & 63;
        float4 v = *(const float4*)(x + ((size_t)(b*CIN + c0 + r))*NPIX + p0 + c4);
        tile[r][c4+0] = v.x; tile[r][c4+1] = v.y; tile[r][c4+2] = v.z; tile[r][c4+3] = v.w;
        float rs = v.x + v.y + v.z + v.w;
        #pragma unroll
        for (int off = 1; off < 16; off <<= 1) rs += __shfl_xor(rs, off, 64);
        if ((t & 15) == 0) atomicAdd(&pooled[b*CIN + c0 + r], rs);
    }
    __syncthreads();
    #pragma unroll
    for (int iter = 0; iter < 4; ++iter){
        int idx = t*4 + iter*1024;
        int pr = idx >> 6, cc = idx & 63;
        ushort4 u;
        u.x = f2bf(tile[cc+0][pr]);
        u.y = f2bf(tile[cc+1][pr]);
        u.z = f2bf(tile[cc+2][pr]);
        u.w = f2bf(tile[cc+3][pr]);
        int p = p0 + pr;
        int yy = p >> 6, xx = p & 63;
        *(ushort4*)(xt2 + ((size_t)b*PPIX + (yy+1)*HP + (xx+1))*CIN + c0 + cc) = u;
    }
}

// -------- 2) aggregated weights + routing + bias; VECTORIZED short8 stores --------
// thread u<288 owns (tap tp=u>>5, cin-group cg=u&31): 16 b128 stores instead of 144 scalar
__global__ __launch_bounds__(320) void k_aggw(
    const float* __restrict__ weight, const float* __restrict__ pooled,
    const float* __restrict__ rw, const float* __restrict__ rb,
    const float* __restrict__ bias,
    u16* __restrict__ aggw, float* __restrict__ aggb)
{
    __shared__ float wls[E_][2304];
    __shared__ float r_s[B_*E_];
    int o = blockIdx.x, t = threadIdx.x;

    if (t < B_*E_){
        int b = t >> 3, e = t & 7;
        const float4* pp = (const float4*)(pooled + b*CIN);
        const float4* wp = (const float4*)(rw + e*CIN);
        float s = 0.f;
        #pragma unroll
        for (int i = 0; i < 64; ++i){
            float4 a = pp[i], c = wp[i];
            s += a.x*c.x + a.y*c.y + a.z*c.z + a.w*c.w;
        }
        s = s * (1.0f/(float)NPIX) + rb[e];
        r_s[t] = 1.0f/(1.0f + __expf(-s));
    }
    #pragma unroll
    for (int e = 0; e < E_; ++e){
        const float4* src = (const float4*)(weight + ((size_t)(e*COUT + o))*2304);
        float4* dst = (float4*)wls[e];
        if (t < 576)       dst[t] = src[t];          // wait: t<320 covers first pass
        int i2 = t + 320;
        if (i2 < 576)      dst[i2] = src[i2];
    }
    __syncthreads();

    if (t < B_){
        float s = 0.f;
        #pragma unroll
        for (int e = 0; e < E_; ++e) s += r_s[t*E_+e]*bias[e*COUT+o];
        aggb[t*COUT + o] = s;
    }

    if (t < 288){
        int tp = t >> 5, cg = t & 31;
        float w[E_][8];
        #pragma unroll
        for (int e = 0; e < E_; ++e)
            #pragma unroll
            for (int j = 0; j < 8; ++j)
                w[e][j] = wls[e][(cg*8 + j)*9 + tp];

        for (int b = 0; b < B_; ++b){
            float acc[8];
            #pragma unroll
            for (int j = 0; j < 8; ++j) acc[j] = 0.f;
            #pragma unroll
            for (int e = 0; e < E_; ++e){
                float r = r_s[b*E_ + e];
                #pragma unroll
                for (int j = 0; j < 8; ++j) acc[j] += r * w[e][j];
            }
            short8 ov;
            #pragma unroll
            for (int jj = 0; jj < 4; ++jj){
                unsigned int d;
                asm("v_cvt_pk_bf16_f32 %0, %1, %2" : "=v"(d) : "v"(acc[2*jj]), "v"(acc[2*jj+1]));
                ov[2*jj]   = (short)(d & 0xFFFF);
                ov[2*jj+1] = (short)(d >> 16);
            }
            *(short8*)(aggw + (((size_t)(b*COUT + o))*9 + tp)*CIN + cg*8) = ov;
        }
    }
}

// -------- 3) k_conv: VERBATIM R4 (best measured: 77.5 us) --------
__global__ __launch_bounds__(512, 2) void k_conv(
    const u16* __restrict__ aggw, const u16* __restrict__ xt2,
    const float* __restrict__ aggb, float* __restrict__ out)
{
    __shared__ __align__(16) u16 lds[65536];   // 2 buf x (A 256x64 + B 256x64) bf16

    int orig = blockIdx.x;
    int bid = (orig & 7)*32 + (orig >> 3);     // bijective XCD swizzle

    int b  = bid >> 4;
    int nt = bid & 15;
    int y0 = nt << 2;

    int t = threadIdx.x;
    int lane = t & 63;
    int w = t >> 6;
    int wm = (w >> 2) << 7;
    int wn = (w & 3) << 6;
    int l16 = lane & 15;
    int kh4 = lane >> 4;
    int sw  = l16 & 7;

    int tr = t >> 3;
    int tc = t & 7;
    int sc = tc ^ (tr & 7);

    const u16* aSrc = aggw + (size_t)b*COUT*9*CIN + (size_t)tr*KTOT + sc*8;
    const u16* bSrc = xt2 + ((size_t)b*PPIX + (size_t)y0*HP + tr)*CIN + sc*8;

    f32x4 acc[8][4];
    #pragma unroll
    for (int i = 0; i < 8; ++i)
        #pragma unroll
        for (int j = 0; j < 4; ++j){
            f32x4 z = {0.f,0.f,0.f,0.f};
            acc[i][j] = z;
        }

    auto stage = [&](int kt, int bufn){
        int tap = kt >> 2;
        int c0  = (kt & 3) << 6;
        int kh  = tap / 3, kw = tap - kh*3;
        const u16* a0 = aSrc + tap*CIN + c0;
        const u16* b0 = bSrc + (kh*HP + kw)*CIN + c0;
        u16* dA = lds + bufn*32768 + w*512;
        u16* dB = dA + 16384;
        #pragma unroll
        for (int i = 0; i < 4; ++i)
            gload(a0 + (size_t)i*64*KTOT, dA + i*4096);
        #pragma unroll
        for (int i = 0; i < 4; ++i)
            gload(b0 + (size_t)i*HP*CIN, dB + i*4096);
    };

    int ck0 = ((kh4    ) ^ sw) * 8;
    int ck1 = ((kh4 | 4) ^ sw) * 8;

    stage(0, 0);
    __syncthreads();

    int buf = 0;
    #pragma unroll 2
    for (int kt = 0; kt < NKT; ++kt){
        const u16* LA = lds + buf*32768;
        const u16* LB = LA + 16384;

        bf16x8 af[2][4][2];    // [qm][mf][khalf]
        bf16x8 bfr[2][2][2];   // [qn][nf][khalf]

        #pragma unroll
        for (int mf = 0; mf < 4; ++mf){
            int ro = (wm + mf*16 + l16) * 64;
            af[0][mf][0] = *(const bf16x8*)(LA + ro + ck0);
            af[0][mf][1] = *(const bf16x8*)(LA + ro + ck1);
        }
        #pragma unroll
        for (int nf = 0; nf < 2; ++nf){
            int ro = (wn + nf*16 + l16) * 64;
            bfr[0][nf][0] = *(const bf16x8*)(LB + ro + ck0);
            bfr[0][nf][1] = *(const bf16x8*)(LB + ro + ck1);
        }

        if (kt < NKT-1) stage(kt+1, buf^1);

        #pragma unroll
        for (int nf = 0; nf < 2; ++nf){
            int ro = (wn + 32 + nf*16 + l16) * 64;
            bfr[1][nf][0] = *(const bf16x8*)(LB + ro + ck0);
            bfr[1][nf][1] = *(const bf16x8*)(LB + ro + ck1);
        }
        #pragma unroll
        for (int mf = 0; mf < 4; ++mf){
            int ro = (wm + 64 + mf*16 + l16) * 64;
            af[1][mf][0] = *(const bf16x8*)(LA + ro + ck0);
            af[1][mf][1] = *(const bf16x8*)(LA + ro + ck1);
        }

        #pragma unroll
        for (int qm = 0; qm < 2; ++qm)
            #pragma unroll
            for (int qn = 0; qn < 2; ++qn){
                __builtin_amdgcn_s_setprio(1);
                #pragma unroll
                for (int mf = 0; mf < 4; ++mf)
                    #pragma unroll
                    for (int nf = 0; nf < 2; ++nf){
                        acc[qm*4+mf][qn*2+nf] = __builtin_amdgcn_mfma_f32_16x16x32_bf16(
                            af[qm][mf][0], bfr[qn][nf][0], acc[qm*4+mf][qn*2+nf], 0, 0, 0);
                        acc[qm*4+mf][qn*2+nf] = __builtin_amdgcn_mfma_f32_16x16x32_bf16(
                            af[qm][mf][1], bfr[qn][nf][1], acc[qm*4+mf][qn*2+nf], 0, 0, 0);
                    }
                __builtin_amdgcn_s_setprio(0);
            }

        __syncthreads();
        buf ^= 1;
    }

    const float* ab = aggb + b*COUT;
    float* outp = out + ((size_t)b*COUT)*NPIX + nt*256;
    #pragma unroll
    for (int mf8 = 0; mf8 < 8; ++mf8){
        #pragma unroll
        for (int v = 0; v < 4; ++v){
            int r = wm + mf8*16 + kh4*4 + v;
            float bias_r = ab[r];
            float* orow = outp + (size_t)r*NPIX;
            #pragma unroll
            for (int nf = 0; nf < 4; ++nf)
                orow[wn + nf*16 + l16] = acc[mf8][nf][v] + bias_r;
        }
    }
}

extern "C" void kernel_launch(void* const* d_in, const int* in_sizes, int n_in,
                              void* d_out, int out_size, void* d_ws, size_t ws_size,
                              hipStream_t stream)
{
    const float* x      = (const float*)d_in[0];
    const float* weight = (const float*)d_in[1];
    const float* bias   = (const float*)d_in[2];
    const float* rw     = (const float*)d_in[3];
    const float* rb     = (const float*)d_in[4];
    float* out = (float*)d_out;

    char* ws = (char*)d_ws;
    u16*   aggw    = (u16*)(ws);                          // 18,874,368 B
    u16*   xt2     = (u16*)(ws + 18874368);               // 35,684,352 B (halo 66x66)
    float* pooled  = (float*)(ws + 54558720);             // 16 KB
    float* aggb    = (float*)(ws + 54558720 + 16384);     // 16 KB

    hipMemsetAsync(pooled, 0, B_*CIN*sizeof(float), stream);
    k_xt   <<<4096, 256, 0, stream>>>(x, xt2, pooled);
    k_aggw <<<COUT, 320, 0, stream>>>(weight, pooled, rw, rb, bias, aggw, aggb);
    k_conv <<<256,  512, 0, stream>>>(aggw, xt2, aggb, out);
}